// Round 6
// baseline (628.655 us; speedup 1.0000x reference)
//
#include <hip/hip_runtime.h>
#include <cstdint>
#include <cstddef>

// ============================================================================
// DualStateLinearAttention on MI355X — round 11
//  R5-R10: five schedule variants all pin at 26-28% MfmaUtil (= m233's
//  drain-0 ~607TF signature). Theory: hipcc's waitcnt pass sees
//  global_load_lds (vmcnt-tracked LDS write) + compiler-visible ds_read of
//  the same arrays -> inserts conservative s_waitcnt vmcnt(0) every phase,
//  overriding every hand-written counted-vmcnt ledger. R11: ds_reads via
//  inline asm (invisible to the pass), rule-18 lgkmcnt(0)+sched_barrier(0)
//  before each MFMA cluster; counted vmcnt(2) per tile is now live.
//  Also fixes R9/R10 silent bug: p0-p2 stagings of tile 2t+1 are now
//  UNCONDITIONAL (old t<15 guard skipped tile31's B-halves; error hid
//  under the bf16 rounding floor).
//  Geometry unchanged: BM=BN=256, 8 waves 2mx4n (per-wave 128x64), dbuf
//  128KB LDS, 8 phases / 2 K-tiles, quadrant order Q00,Q01,Q11,Q10.
// Pipeline: cvt -> proj(5x fused) -> gc -> [sA -> s2 -> s3b] x2 -> out-GEMM.
// ============================================================================

#define BB     2
#define SEQ    2048
#define HIDN   2048
#define NH     16
#define DD     128
#define CHUNK  64
#define NCHUNK (SEQ / CHUNK)   // 32
#define NBH    (BB * NH)       // 32
#define NELC   8388608
#define WELC   4194304
static constexpr float QSCALE = 0.08838834764831845f;  // 128^-0.5

typedef __bf16 bf16_t;
typedef _Float16 half_t;
typedef short  short8 __attribute__((ext_vector_type(8)));
typedef float  f32x4  __attribute__((ext_vector_type(4)));

__device__ __forceinline__ float bf2f(short u) {
  return (float)__builtin_bit_cast(bf16_t, u);
}
__device__ __forceinline__ short f2bf(float f) {
  return __builtin_bit_cast(short, (bf16_t)f);
}
__device__ __forceinline__ float hf2f(short u) {
  return (float)__builtin_bit_cast(half_t, u);
}
__device__ __forceinline__ short f2hf(float f) {
  return __builtin_bit_cast(short, (half_t)f);
}

__device__ __forceinline__ void gload_lds16(const void* g, void* l) {
  __builtin_amdgcn_global_load_lds(
      (__attribute__((address_space(1))) unsigned int*)g,
      (__attribute__((address_space(3))) unsigned int*)l, 16, 0, 0);
}

// inline-asm ds_read_b128: hidden from the compiler's waitcnt pass, so no
// conservative vmcnt(0) drain is inserted before it. Data valid only after
// an explicit lgkmcnt(0) (see WAIT_LDS).
__device__ __forceinline__ short8 ldsr128(const short* p) {
  short8 r;
  asm volatile("ds_read_b128 %0, %1"
               : "=v"(r)
               : "v"((unsigned)(unsigned long long)
                         (__attribute__((address_space(3))) const short*)p));
  return r;
}

#define VMW2 asm volatile("s_waitcnt vmcnt(2)" ::: "memory")
#define VMW0 asm volatile("s_waitcnt vmcnt(0)" ::: "memory")
// rule #18: lgkmcnt(0) for asm ds_reads + sched_barrier so MFMA can't hoist
#define WAIT_LDS                                          \
  do {                                                    \
    asm volatile("s_waitcnt lgkmcnt(0)" ::: "memory");    \
    __builtin_amdgcn_sched_barrier(0);                    \
  } while (0)
#define SBAR __builtin_amdgcn_s_barrier()

// ---------------------------------------------------------------------------
// 256x256 bf16 MFMA GEMM, BK=64, 8 waves (2m x 4n, per-wave 128x64),
// dbuf LDS (128KB), 8 phases / 2 K-tiles, counted vmcnt(2) at p3/p7.
// Gather swizzle: LDS[r][chunk c] = G[r][chunk c^(r&7)] (involution, both
// sides) — conflict-free ds_read_b128 (SQ_LDS_BANK_CONFLICT=0, R5-R10).
// Stage-halves match read-halves exactly:
//   A-half h: rows {h*64..h*64+63} u {h*64+128..h*64+191}  (= LDA(h) rows)
//   B-half h: rows == [h*32,(h+1)*32) mod 64               (= LDB2(2h) rows)
// ---------------------------------------------------------------------------

#define STG_A(buf, kt, h)                                                   \
  {                                                                         \
    const size_t ko = (size_t)(kt) * 64;                                    \
    gload_lds16(Ag + (size_t)((h) * 64) * HIDN + ko,                        \
                (void*)&As[buf][((h) * 64 + wave * 8) * 64]);               \
    gload_lds16(Ag + (size_t)((h) * 64 + 128) * HIDN + ko,                  \
                (void*)&As[buf][((h) * 64 + 128 + wave * 8) * 64]);         \
  }

#define STG_B(buf, kt, h)                                                   \
  {                                                                         \
    const int cb0 = (wave >> 2) * 64 + (h) * 32 + (wave & 3) * 8;           \
    const size_t ko = (size_t)(kt) * 64;                                    \
    gload_lds16(Bg + (size_t)cb0 * HIDN + ko,                               \
                (void*)&Bs[buf][cb0 * 64]);                                 \
    gload_lds16(Bg + (size_t)(cb0 + 128) * HIDN + ko,                       \
                (void*)&Bs[buf][(cb0 + 128) * 64]);                         \
  }

// load A-frags (4) for m-half mh from buffer rb into af[0..3][ks]  (asm)
#define LDA(mh, rb)                                                         \
  {                                                                         \
    _Pragma("unroll") for (int f = 0; f < 4; f++) {                         \
      const int row = wm * 128 + (mh) * 64 + f * 16 + l16;                  \
      af[f][0] = ldsr128(&As[rb][row * 64 + ((qd ^ ro) << 3)]);             \
      af[f][1] = ldsr128(&As[rb][row * 64 + (((4 + qd) ^ ro) << 3)]);       \
    }                                                                       \
  }

// load B-frags (2) j0..j0+1 from buffer rb into bfr[j0..j0+1][ks]  (asm)
#define LDB2(j0, rb)                                                        \
  {                                                                         \
    _Pragma("unroll") for (int g = 0; g < 2; g++) {                         \
      const int col = wn * 64 + ((j0) + g) * 16 + l16;                      \
      bfr[(j0) + g][0] =                                                    \
          ldsr128(&Bs[rb][col * 64 + ((qd ^ ro) << 3)]);                    \
      bfr[(j0) + g][1] =                                                    \
          ldsr128(&Bs[rb][col * 64 + (((4 + qd) ^ ro) << 3)]);              \
    }                                                                       \
  }

// MFMA one quadrant (mh, nh)
#define MQ(mh, nh)                                                          \
  {                                                                         \
    __builtin_amdgcn_s_setprio(1);                                          \
    _Pragma("unroll") for (int ks = 0; ks < 2; ks++)                        \
    _Pragma("unroll") for (int f = 0; f < 4; f++)                           \
    _Pragma("unroll") for (int g = 0; g < 2; g++)                           \
      acc[(mh) * 4 + f][(nh) * 2 + g] =                                     \
          __builtin_amdgcn_mfma_f32_16x16x32_bf16(                          \
              af[f][ks], bfr[(nh) * 2 + g][ks],                             \
              acc[(mh) * 4 + f][(nh) * 2 + g], 0, 0, 0);                    \
    __builtin_amdgcn_s_setprio(0);                                          \
  }

__device__ __forceinline__ void gemm256(const bf16_t* __restrict__ A,
                                        const bf16_t* __restrict__ Bw,
                                        const float*  __restrict__ bias,
                                        bf16_t* __restrict__ outb,
                                        float*  __restrict__ outf, int epi) {
  __shared__ short As[2][256 * 64];  // 64 KB
  __shared__ short Bs[2][256 * 64];  // 64 KB
  const int tm   = blockIdx.x * 256;
  const int tn   = blockIdx.y * 256;
  const int tid  = threadIdx.x;
  const int wave = tid >> 6;
  const int lane = tid & 63;
  const int wm   = wave >> 2;  // 0..1 -> 128 output rows each
  const int wn   = wave & 3;   // 0..3 -> 64 output cols each
  const int qd   = lane >> 4;
  const int l16  = lane & 15;
  const int ro   = l16 & 7;
  const int gc   = (lane & 7) ^ (lane >> 3);

  // A staging base includes wave*8 (STG_A row = h*64 [+128] + wave*8 + l>>3);
  // B staging base does NOT (cb0 encodes the wave offset).
  const short* Ag =
      (const short*)A + (size_t)(tm + wave * 8 + (lane >> 3)) * HIDN + gc * 8;
  const short* Bg =
      (const short*)Bw + (size_t)(tn + (lane >> 3)) * HIDN + gc * 8;

  f32x4 acc[8][4];
#pragma unroll
  for (int i = 0; i < 8; i++)
#pragma unroll
    for (int j = 0; j < 4; j++) acc[i][j] = (f32x4){0.f, 0.f, 0.f, 0.f};
  short8 af[4][2], bfr[4][2];

  // prologue: tile0's 4 halves + tile1's A-h0 (10 loads); vmcnt(2) drains
  // tile0, leaves tile1.Ah0 in flight == steady-state p7-exit condition.
  STG_A(0, 0, 0); STG_A(0, 0, 1); STG_B(0, 0, 0); STG_B(0, 0, 1);
  STG_A(1, 1, 0);
  VMW2;
  SBAR;

  // Ledger (steady, per iteration; outstanding in halves of 2 loads):
  //  p7(prev) leaves 2 (Ah0 2t+1). p0..p2 stage tile 2t+1 Ah1/Bh0/Bh1
  //  (out 4,6,8). p3 stages Ah0(2t+2) (out 10) then VMW2 drains the 8
  //  oldest = ALL of tile 2t+1 -> read in p4-p7. p4..p6 stage tile 2t+2
  //  Ah1/Bh0/Bh1, p7 stages Ah0(2t+3) (out 10), VMW2 drains tile 2t+2.
  for (int t = 0; t < 16; t++) {
    // ===== K-tile 2t (buf0) =====
    // p0: Q(0,0) reads Ah0+B(j01); stage T{2t+1}.Ah1  (2t+1<=31: no guard)
    LDA(0, 0); LDB2(0, 0);
    STG_A(1, 2 * t + 1, 1);
    SBAR; WAIT_LDS; MQ(0, 0); SBAR;
    // p1: Q(0,1) reads B(j23); stage T{2t+1}.Bh0  (UNCONDITIONAL — R11 fix)
    LDB2(2, 0);
    STG_B(1, 2 * t + 1, 0);
    SBAR; WAIT_LDS; MQ(0, 1); SBAR;
    // p2: Q(1,1) reads Ah1; stage T{2t+1}.Bh1  (UNCONDITIONAL — R11 fix)
    LDA(1, 0);
    STG_B(1, 2 * t + 1, 1);
    SBAR; WAIT_LDS; MQ(1, 1); SBAR;
    // p3: Q(1,0) no reads; stage T{2t+2}.Ah0; drain tile 2t+1
    if (t < 15) { STG_A(0, 2 * t + 2, 0); }
    MQ(1, 0);
    if (t < 15) { VMW2; } else { VMW0; }
    SBAR;
    // ===== K-tile 2t+1 (buf1) =====
    // p4: Q(0,0); stage T{2t+2}.Ah1
    LDA(0, 1); LDB2(0, 1);
    if (t < 15) { STG_A(0, 2 * t + 2, 1); }
    SBAR; WAIT_LDS; MQ(0, 0); SBAR;
    // p5: Q(0,1); stage T{2t+2}.Bh0
    LDB2(2, 1);
    if (t < 15) { STG_B(0, 2 * t + 2, 0); }
    SBAR; WAIT_LDS; MQ(0, 1); SBAR;
    // p6: Q(1,1); stage T{2t+2}.Bh1
    LDA(1, 1);
    if (t < 15) { STG_B(0, 2 * t + 2, 1); }
    SBAR; WAIT_LDS; MQ(1, 1); SBAR;
    // p7: Q(1,0); stage T{2t+3}.Ah0; drain tile 2t+2
    if (t < 15) { STG_A(1, 2 * t + 3, 0); }
    MQ(1, 0);
    if (t < 15) { VMW2; }
    SBAR;
  }

  // epilogue: row = tm + wm*128 + (i>>2)*64 + (i&3)*16 + qd*4 + r
  //           col = tn + wn*64 + j*16 + l16
#pragma unroll
  for (int i = 0; i < 8; i++)
#pragma unroll
    for (int j = 0; j < 4; j++)
#pragma unroll
      for (int r = 0; r < 4; r++) {
        const int row =
            tm + wm * 128 + (i >> 2) * 64 + (i & 3) * 16 + qd * 4 + r;
        const int col = tn + wn * 64 + j * 16 + l16;
        float v = acc[i][j][r];
        if (epi == 1) {
          v += bias[col];
          const float ls = fminf(v, 0.f) - log1pf(__expf(-fabsf(v)));
          v = fmaxf(ls * 0.0625f, -50.f);
        }
        if (epi == 2) outf[(size_t)row * HIDN + col] = v;
        else          outb[(size_t)row * HIDN + col] = (bf16_t)v;
      }
}

__global__ __launch_bounds__(512, 2) void k_gemm_proj(
    const bf16_t* __restrict__ Xb,
    const bf16_t* __restrict__ W0, const bf16_t* __restrict__ W1,
    const bf16_t* __restrict__ W2, const bf16_t* __restrict__ W3,
    const bf16_t* __restrict__ W4,
    const float* __restrict__ bg1, const float* __restrict__ bg2,
    bf16_t* __restrict__ Qb, bf16_t* __restrict__ Kb, bf16_t* __restrict__ Vb,
    bf16_t* __restrict__ G1b, bf16_t* __restrict__ G2b) {
  const int z = blockIdx.z;
  const bf16_t* Ws[5] = {W0, W1, W2, W3, W4};
  bf16_t* Os[5] = {Qb, Kb, Vb, G1b, G2b};
  const float* bias = (z == 3) ? bg1 : ((z == 4) ? bg2 : nullptr);
  gemm256(Xb, Ws[z], bias, Os[z], nullptr, (z >= 3) ? 1 : 0);
}

__global__ __launch_bounds__(512, 2) void k_gemm_out(
    const bf16_t* __restrict__ attnB, const bf16_t* __restrict__ Wob,
    float* __restrict__ out) {
  gemm256(attnB, Wob, nullptr, nullptr, out, 2);
}

// ---------------------------------------------------------------------------
__global__ __launch_bounds__(256) void k_cvt_all(
    const float* __restrict__ hid, const float* __restrict__ wq,
    const float* __restrict__ wk, const float* __restrict__ wv,
    const float* __restrict__ wg1, const float* __restrict__ wg2,
    const float* __restrict__ wo, bf16_t* __restrict__ Xb,
    bf16_t* __restrict__ Wd, bf16_t* __restrict__ Wcur,
    bf16_t* __restrict__ WoB) {
  const int y = blockIdx.y;
  const float* srcs[7] = {hid, wq, wk, wv, wg1, wg2, wo};
  bf16_t* dsts[7] = {Xb, Wd, Wd + WELC, Wd + 2 * WELC, Wd + 3 * WELC, Wcur,
                     WoB};
  const int n = (y == 0) ? NELC : WELC;
  const float* src = srcs[y];
  bf16_t* dst = dsts[y];
  const int idx = (blockIdx.x * 256 + threadIdx.x) * 4;
  if (idx < n) {
    const float4 f = *(const float4*)(src + idx);
    dst[idx + 0] = (bf16_t)f.x; dst[idx + 1] = (bf16_t)f.y;
    dst[idx + 2] = (bf16_t)f.z; dst[idx + 3] = (bf16_t)f.w;
  }
}

__global__ __launch_bounds__(256) void k_zero(float* __restrict__ out) {
  out[(size_t)blockIdx.x * 256 + threadIdx.x] = 0.f;
}

// ---------------------------------------------------------------------------
// k_gc: per-chunk inclusive cumsum of gate values along t (fp32 accum),
// stored fp16 IN PLACE over G; chunk totals to Btot (fp32).
// grid (NCHUNK, BB*4, 2), 64 threads. Fully coalesced b128.
// ---------------------------------------------------------------------------
__global__ __launch_bounds__(64) void k_gc(bf16_t* __restrict__ G1b,
                                           bf16_t* __restrict__ G2b,
                                           float* __restrict__ Btot) {
  const int n = blockIdx.x, b = blockIdx.y >> 2, slab = blockIdx.y & 3;
  const int e = blockIdx.z;
  short* P = (short*)(e ? G2b : G1b);
  const int d0 = slab * 512 + threadIdx.x * 8;
  const size_t base = ((size_t)(b * SEQ + n * CHUNK)) * HIDN + d0;
  float c[8] = {0.f, 0.f, 0.f, 0.f, 0.f, 0.f, 0.f, 0.f};
  for (int t = 0; t < CHUNK; t++) {
    short* p = P + base + (size_t)t * HIDN;
    const short8 g = *(const short8*)p;
    short8 o;
#pragma unroll
    for (int j = 0; j < 8; j++) { c[j] += bf2f(g[j]); o[j] = f2hf(c[j]); }
    *(short8*)p = o;
  }
  const int bh = b * 16 + (d0 >> 7);
  float* bp = Btot + ((size_t)(e * NBH + bh) * NCHUNK + n) * DD + (d0 & 127);
#pragma unroll
  for (int j = 0; j < 8; j++) bp[j] = c[j];
}

// ---------------------------------------------------------------------------
// k_sA (per e): fused U-build + intra-chunk output.
//   vT[dv][s](pad66), khatT[dk][s](pad66), k2[s][d](swz), qh[t][d](swz),
//   Ps[t][s](pad72).  U = vT x khatT -> UT global (chunk-swizzled rows).
//   P = qh x k2 (causal), o_intra = Ps x vT -> attn (w_e folded).
// ---------------------------------------------------------------------------
template <int ACC>
__global__ __launch_bounds__(256) void k_sA(
    const bf16_t* __restrict__ Qb, const bf16_t* __restrict__ Kb,
    const bf16_t* __restrict__ Vb, const bf16_t* __restrict__ Gc,
    bf16_t* __restrict__ UT, const float* __restrict__ alpha,
    bf16_t* __restrict__ attn) {
  const int n = blockIdx.x, bh = blockIdx.y;
  const int b = bh >> 4, h = bh & 15;
  const size_t rbase = ((size_t)(b * SEQ + n * CHUNK)) * HIDN + h * DD;
  const int tid = threadIdx.x;
  const int wave = tid >> 6, lane = tid & 63, qd = lane >> 4, l16 = lane & 15;
  __shared__ short vT[128 * 66];
  __shared__ short k2s[64 * 128];
  __shared__ short r3[128 * 66];  // khatT, then reused as qh (64*128 prefix)
  __shared__ short Ps[64 * 72];
  const float mx = fmaxf(alpha[0], alpha[1]);
  const float x0 = __expf(alpha[0] - mx), x1 = __expf(alpha[1] - mx);
  const float wsc = ((ACC ? x1 : x0) / (x0 + x1)) * QSCALE;

  const short* Kp = (const short*)Kb;
  const short* Vp = (const short*)Vb;
  const short* Gp = (const short*)Gc;
  const short* Qp = (const short*)Qb;

  // builds: vT (col-writes, bank d mod 32), k2 (swz b128), khatT (col-writes)
#pragma unroll
  for (int rep = 0; rep < 4; rep++) {
    const int slot = rep * 256 + tid;
    const int t = slot >> 4, ch = slot & 15;
    const size_t ga = rbase + (size_t)t * HIDN + ch * 8;
    const short8 vv = *(const short8*)(Vp + ga);
    const short8 kk = *(const short8*)(Kp + ga);
    const short8 cc = *(const short8*)(Gp + ga);
    const short8 c6 = *(const short8*)(Gp + rbase + (size_t)63 * HIDN + ch * 8);
    short8 k2v;
#pragma unroll
    for (int j = 0; j < 8; j++) {
      const int d = ch * 8 + j;
      vT[d * 66 + t] = vv[j];
      const float c = hf2f(cc[j]);
      const float kf = bf2f(kk[j]);
      k2v[j] = f2bf(kf * __expf(-c));
      r3[d * 66 + t] = f2bf(kf * __expf(hf2f(c6[j]) - c));
    }
    *(short8*)&k2s[t * 128 + ((ch ^ (t & 7)) << 3)] = k2v;
  }
  __syncthreads();

  {  // U-MFMA: C[dv][dk] = sum_s vT[dv][s] * khatT[dk][s]
    const int m0 = (wave >> 1) * 64, n0 = (wave & 1) * 64;
    const int* vTi = (const int*)vT;
    const int* r3i = (const int*)r3;
    f32x4 uacc[4][4];
#pragma unroll
    for (int i = 0; i < 4; i++)
#pragma unroll
      for (int j = 0; j < 4; j++) uacc[i][j] = (f32x4){0.f, 0.f, 0.f, 0.f};
#pragma unroll
    for (int ks = 0; ks < 2; ks++) {
      const int ch = ks * 4 + qd;
      short8 af[4], bfv[4];
#pragma unroll
      for (int i = 0; i < 4; i++) {
        const int dv = m0 + i * 16 + l16;
        const int ba = dv * 33 + ch * 4;
#pragma unroll
        for (int w2 = 0; w2 < 4; w2++) {
          const int v = vTi[ba + w2];
          af[i][2 * w2] = (short)(v & 0xffff);
          af[i][2 * w2 + 1] = (short)((unsigned)v >> 16);
        }
      }
#pragma unroll
      for (int j = 0; j < 4; j++) {
        const int dk = n0 + j * 16 + l16;
        const int ba = dk * 33 + ch * 4;
#pragma unroll
        for (int w2 = 0; w2 < 4; w2++) {
          const int v = r3i[ba + w2];
          bfv[j][2 * w2] = (short)(v & 0xffff);
          bfv[j][2 * w2 + 1] = (short)((unsigned)v >> 16);
        }
      }
#pragma unroll
      for (int i = 0; i < 4; i++)
#pragma unroll
        for (int j = 0; j < 4; j++)
          uacc[i][j] = __builtin_amdgcn_mfma_f32_16x16x32_bf16(
              af[i], bfv[j], uacc[i][j], 0, 0, 0);
    }
    short* Uo = (short*)UT + (size_t)(bh * NCHUNK + n) * (DD * DD);
#pragma unroll
    for (int i = 0; i < 4; i++)
#pragma unroll
      for (int j = 0; j < 4; j++)
#pragma unroll
        for (int r = 0; r < 4; r++) {
          const int dv = m0 + i * 16 + qd * 4 + r;
          const int dk = n0 + j * 16 + l16;
          Uo[dv * 128 + (((dk >> 3) ^ (dv & 7)) << 3) + (dk & 7)] =
              f2bf(uacc[i][j][r]);
        }
  }
  __syncthreads();

  // qh build (overwrites khatT region)
#pragma unroll
  for (int rep = 0; rep < 4; rep++) {
    const int slot = rep * 256 + tid;
    const int t = slot >> 4, ch = slot & 15;
    const size_t ga = rbase + (size_t)t * HIDN + ch * 8;
    const short8 qq = *(const short8*)(Qp + ga);
    const short8 cc = *(const short8*)(Gp + ga);
    short8 o;
#pragma unroll
    for (int j = 0; j < 8; j++)
      o[j] = f2bf(bf2f(qq[j]) * wsc * __expf(hf2f(cc[j])));
    *(short8*)&r3[t * 128 + ((ch ^ (t & 7)) << 3)] = o;
  }
  __syncthreads();

  {  // P = qh x k2 (causal): wave owns t-rows [wave*16, +16)
    f32x4 pacc[4];
#pragma unroll
    for (int j = 0; j < 4; j++) pacc[j] = (f32x4){0.f, 0.f, 0.f, 0.f};
    const int tq = wave * 16 + l16;
#pragma unroll
    for (int ks = 0; ks < 4; ks++) {
      const int ch = ks * 4 + qd;
      const short8 a = *(const short8*)&r3[tq * 128 + ((ch ^ (tq & 7)) << 3)];
#pragma unroll
      for (int j = 0; j < 4; j++) {
        const int s = j * 16 + l16;
        const short8 bq =
            *(const short8*)&k2s[s * 128 + ((ch ^ (s & 7)) << 3)];
        pacc[j] =
            __builtin_amdgcn_mfma_f32_16x16x32_bf16(a, bq, pacc[j], 0, 0, 0);
      }
    }
#pragma unroll
    for (int j = 0; j < 4; j++)
#pragma unroll
      for (int r = 0; r < 4; r++) {
        const int t = wave * 16 + qd * 4 + r, s = j * 16 + l16;
        Ps[t * 72 + s] = (t >= s) ? f2bf(pacc[j][r]) : (short)0;
      }
  }
  __syncthreads();

  // o_intra = Ps x vT
  f32x4 oacc[8];
#pragma unroll
  for (int j = 0; j < 8; j++) oacc[j] = (f32x4){0.f, 0.f, 0.f, 0.f};
  {
    const int* vTi = (const int*)vT;
    const int tq = wave * 16 + l16;
#pragma unroll
    for (int ks = 0; ks < 2; ks++) {
      const int ch = ks * 4 + qd;
      const short8 a = *(const short8*)&Ps[tq * 72 + ch * 8];
#pragma unroll
      for (int j = 0; j < 8; j++) {
        const int dv = j * 16 + l16;
        const int ba = dv * 33 + ch * 4;
        short8 bq;
#pragma unroll
        for (int w2 = 0; w2 < 4; w2++) {
          const int v = vTi[ba + w2];
          bq[2 * w2] = (short)(v & 0xffff);
          bq[2 * w2 + 1] = (short)((unsigned)v >> 16);
        }
        oacc[j] =
            __builtin_amdgcn_mfma_f32_16x16x32_bf16(a, bq, oacc[j], 0, 0, 0);
      }
    }
  }
#pragma unroll
  for (int j = 0; j < 8; j++)
#pragma unroll
    for (int r = 0; r < 4; r++) {
      const int t = wave * 16 + qd * 4 + r;
      const int dv = j * 16 + l16;
      bf16_t* p = &attn[rbase + (size_t)t * HIDN + dv];
      if (ACC) *p = (bf16_t)((float)*p + oacc[j][r]);
      else     *p = (bf16_t)oacc[j][r];
    }
}

// ---------------------------------------------------------------------------
// k_s2: sequential chunk combine (swizzled UT rows); S^T in place.
// ---------------------------------------------------------------------------
__global__ __launch_bounds__(256) void k_s2(bf16_t* __restrict__ UT,
                                            const float* __restrict__ Btot) {
  const int dg = blockIdx.x, bh = blockIdx.y;
  const int dv = dg * 8 + (threadIdx.x >> 5);
  const int dk0 = (threadIdx.x & 31) * 4;
  const int pos = dv * 128 + (((dk0 >> 3) ^ (dv & 7)) << 3) + (dk0 & 7);
  float st[4] = {0.f, 0.f, 0.f, 0.f};
  for (int nn = 0; nn < NCHUNK; nn++) {
    short* p = (short*)UT + (size_t)(bh * NCHUNK + nn) * (DD * DD) + pos;
    const float4 bp =
        *(const float4*)(Btot + (size_t)(bh * NCHUNK + nn) * DD + dk0);
    short u0 = p[0], u1 = p[1], u2 = p[2], u3 = p[3];
    p[0] = f2bf(st[0]); p[1] = f2bf(st[1]);
    p[2] = f2bf(st[2]); p[3] = f2bf(st[3]);
    st[0] = st[0] * __expf(bp.x) + bf2f(u0);
    st[1] = st[1] * __expf(bp.y) + bf2f(u1);
    st[2] = st[2] * __expf(bp.z) + bf2f(u2);
    st[3] = st[3] * __expf(bp.w) + bf2f(u3);
  }
}

// ---------------------------------------------------------------------------
// k_s3b: inter-chunk  attn += qh @ S.  S staged via gload16 (async, overlaps
// qh rebuild); both read as swizzled b128 frags.
// ---------------------------------------------------------------------------
__global__ __launch_bounds__(256) void k_s3b(
    const bf16_t* __restrict__ Qb, const bf16_t* __restrict__ Gc,
    const bf16_t* __restrict__ UT, const float* __restrict__ alpha,
    const int e, bf16_t* __restrict__ attn) {
  const int n = blockIdx.x, bh = blockIdx.y;
  const int b = bh >> 4, h = bh & 15;
  const size_t rbase = ((size_t)(b * SEQ + n * CHUNK)) * HIDN + h * DD;
  const int tid = threadIdx.x;
  const int wave = tid >> 6, lane = tid & 63, qd = lane >> 4, l16 = lane & 15;
  __shared__ short qh[64 * 128];
  __shared__ short Ss[128 * 128];
  const float mx = fmaxf(alpha[0], alpha[1]);
  const float x0 = __expf(alpha[0] - mx), x1 = __expf(alpha[1] - mx);
  const float wsc = ((e ? x1 : x0) / (x0 + x1)) * QSCALE;

  // async-stage S tile (2048 x 16B chunks, lane-linear, layout preserved)
  const short* Sp = (const short*)UT + (size_t)(bh * NCHUNK + n) * (DD * DD);
#pragma unroll
  for (int rep = 0; rep < 8; rep++) {
    const int c = rep * 256 + tid;
    gload_lds16(Sp + c * 8, &Ss[c * 8]);
  }
  // qh rebuild (overlaps the async loads)
  const short* Qp = (const short*)Qb;
  const short* Gp = (const short*)Gc;
#pragma unroll
  for (int rep = 0; rep < 4; rep++) {
    const int slot = rep * 256 + tid;
    const int t = slot >> 4, ch = slot & 15;
    const size_t ga = rbase + (size_t)t * HIDN + ch * 8;
    const short8 qq = *(const short8*)(Qp + ga);
    const short8 cc = *(const short8*)(Gp + ga);
    short8 o;
#pragma unroll
    for (int j = 0; j < 8; j++)
      o[j] = f2bf(bf2f(qq[j]) * wsc * __expf(hf2f(cc[j])));
    *(short8*)&qh[t * 128 + ((ch ^ (t & 7)) << 3)] = o;
  }
  __syncthreads();

  f32x4 oacc[8];
#pragma unroll
  for (int j = 0; j < 8; j++) oacc[j] = (f32x4){0.f, 0.f, 0.f, 0.f};
  const int tq = wave * 16 + l16;
#pragma unroll
  for (int ks = 0; ks < 4; ks++) {
    const int ch = ks * 4 + qd;
    const short8 a = *(const short8*)&qh[tq * 128 + ((ch ^ (tq & 7)) << 3)];
#pragma unroll
    for (int j = 0; j < 8; j++) {
      const int dv = j * 16 + l16;
      const short8 bq = *(const short8*)&Ss[dv * 128 + ((ch ^ (dv & 7)) << 3)];
      oacc[j] =
          __builtin_amdgcn_mfma_f32_16x16x32_bf16(a, bq, oacc[j], 0, 0, 0);
    }
  }
#pragma unroll
  for (int j = 0; j < 8; j++)
#pragma unroll
    for (int r = 0; r < 4; r++) {
      const int t = wave * 16 + qd * 4 + r;
      const int dv = j * 16 + l16;
      bf16_t* p = &attn[rbase + (size_t)t * HIDN + dv];
      *p = (bf16_t)((float)*p + oacc[j][r]);
    }
}

// ---------------------------------------------------------------------------
extern "C" void kernel_launch(void* const* d_in, const int* in_sizes, int n_in,
                              void* d_out, int out_size, void* d_ws,
                              size_t ws_size, hipStream_t stream) {
  const float* hid  = (const float*)d_in[0];
  const float* wq   = (const float*)d_in[1];
  const float* wk   = (const float*)d_in[2];
  const float* wv   = (const float*)d_in[3];
  const float* wo   = (const float*)d_in[4];
  const float* wg1  = (const float*)d_in[5];
  const float* bg1  = (const float*)d_in[6];
  const float* wg2  = (const float*)d_in[7];
  const float* bg2  = (const float*)d_in[8];
  const float* alph = (const float*)d_in[9];
  float* out = (float*)d_out;
  (void)in_sizes; (void)n_in; (void)out_size;

  char* ws = (char*)d_ws;
  size_t off = 0;
  auto alloc = [&](size_t bytes) -> void* {
    void* p = ws + off;
    off += (bytes + 255) & ~(size_t)255;
    return p;
  };
  const size_t NEL = NELC, WEL = WELC;
  bf16_t* Xb   = (bf16_t*)alloc(NEL * 2);  // X; reused as attn
  bf16_t* Wcur = (bf16_t*)alloc(WEL * 2);  // Wg2
  bf16_t* WoB  = (bf16_t*)alloc(WEL * 2);  // Wo
  bf16_t* Qb   = (bf16_t*)alloc(NEL * 2);
  bf16_t* Kb   = (bf16_t*)alloc(NEL * 2);
  bf16_t* Vb   = (bf16_t*)alloc(NEL * 2);
  bf16_t* G1b  = (bf16_t*)alloc(NEL * 2);
  bf16_t* G2b  = (bf16_t*)alloc(NEL * 2);
  float*  Btot = (float*) alloc((size_t)2 * NBH * NCHUNK * DD * 4);
  bf16_t* Wd = (bf16_t*)d_out;  // weights, then U/S states, then final out
  bf16_t* UT = (bf16_t*)d_out;

  if (off > ws_size) {  // diagnostic fallback
    k_zero<<<dim3((unsigned)(NEL / 256)), 256, 0, stream>>>(out);
    return;
  }

  k_cvt_all<<<dim3(8192, 7), 256, 0, stream>>>(hid, wq, wk, wv, wg1, wg2, wo,
                                               Xb, Wd, Wcur, WoB);
  k_gemm_proj<<<dim3(16, 8, 5), 512, 0, stream>>>(
      Xb, Wd, Wd + WEL, Wd + 2 * WEL, Wd + 3 * WEL, Wcur, bg1, bg2, Qb, Kb, Vb,
      G1b, G2b);
  k_gc<<<dim3(NCHUNK, BB * 4, 2), 64, 0, stream>>>(G1b, G2b, Btot);

  const dim3 gs(NCHUNK, NBH), g2(16, NBH);
  const size_t BSTRIDE = (size_t)NBH * NCHUNK * DD;
  // e = 0
  k_sA<0><<<gs, 256, 0, stream>>>(Qb, Kb, Vb, G1b, UT, alph, Xb);
  k_s2<<<g2, 256, 0, stream>>>(UT, Btot);
  k_s3b<<<gs, 256, 0, stream>>>(Qb, G1b, UT, alph, 0, Xb);
  // e = 1
  k_sA<1><<<gs, 256, 0, stream>>>(Qb, Kb, Vb, G2b, UT, alph, Xb);
  k_s2<<<g2, 256, 0, stream>>>(UT, Btot + BSTRIDE);
  k_s3b<<<gs, 256, 0, stream>>>(Qb, G2b, UT, alph, 1, Xb);

  k_gemm_out<<<dim3(16, 8), 512, 0, stream>>>(Xb, WoB, out);
}

// Round 7
// 576.842 us; speedup vs baseline: 1.0898x; 1.0898x over previous
//
#include <hip/hip_runtime.h>
#include <cstdint>
#include <cstddef>

// ============================================================================
// DualStateLinearAttention on MI355X — round 12
//  R11 post-mortem: asm-hidden ds_reads = no change (compiler-vmcnt theory
//  falsified) + spill (+33MB WRITE). Model that closes: linear blockIdx
//  round-robins XCDs -> panel-sharing blocks on different L2s -> staging
//  loads are L2 misses (~500-900cy); R10's ledger gave only 3-phase cover,
//  so phase time equilibrates at ~latency/3 -> ~28% MfmaUtil regardless of
//  schedule (R6-R11 all identical). R12 attacks both ends:
//   (1) 4-phase cover: stage p0:{Ah0'+Bh0'} p1:{Bh1'} p2:{Ah1'};
//       drains vmcnt(6)@p0, vmcnt(6)@p1, vmcnt(4)@p3 — never below 4;
//       3 barriers/tile; every drained load staged exactly 4 phases prior.
//   (2) T1 XCD swizzle: lid%8 -> 4x4 block cluster per XCD (bijective);
//       co-L2 blocks share 4 A + 4 B panels -> misses become L2 hits.
//   (3) plain ds_reads again (no asm, no sched_barrier, no spill).
// Pipeline: cvt -> proj(5x fused) -> gc -> [sA -> s2 -> s3b] x2 -> out-GEMM.
// ============================================================================

#define BB     2
#define SEQ    2048
#define HIDN   2048
#define NH     16
#define DD     128
#define CHUNK  64
#define NCHUNK (SEQ / CHUNK)   // 32
#define NBH    (BB * NH)       // 32
#define NELC   8388608
#define WELC   4194304
static constexpr float QSCALE = 0.08838834764831845f;  // 128^-0.5

typedef __bf16 bf16_t;
typedef _Float16 half_t;
typedef short  short8 __attribute__((ext_vector_type(8)));
typedef float  f32x4  __attribute__((ext_vector_type(4)));

__device__ __forceinline__ float bf2f(short u) {
  return (float)__builtin_bit_cast(bf16_t, u);
}
__device__ __forceinline__ short f2bf(float f) {
  return __builtin_bit_cast(short, (bf16_t)f);
}
__device__ __forceinline__ float hf2f(short u) {
  return (float)__builtin_bit_cast(half_t, u);
}
__device__ __forceinline__ short f2hf(float f) {
  return __builtin_bit_cast(short, (half_t)f);
}

__device__ __forceinline__ void gload_lds16(const void* g, void* l) {
  __builtin_amdgcn_global_load_lds(
      (__attribute__((address_space(1))) unsigned int*)g,
      (__attribute__((address_space(3))) unsigned int*)l, 16, 0, 0);
}

#define VMW6 asm volatile("s_waitcnt vmcnt(6)" ::: "memory")
#define VMW4 asm volatile("s_waitcnt vmcnt(4)" ::: "memory")
#define VMW2 asm volatile("s_waitcnt vmcnt(2)" ::: "memory")
#define VMW0 asm volatile("s_waitcnt vmcnt(0)" ::: "memory")
#define SBAR __builtin_amdgcn_s_barrier()

// ---------------------------------------------------------------------------
// 256x256 bf16 MFMA GEMM, BK=64, 8 waves (2m x 4n, per-wave 128x64),
// dbuf LDS (128KB). 4 phases/K-tile, quadrant order Q00,Q01,Q11,Q10.
// Gather swizzle: LDS[r][chunk c] = G[r][chunk c^(r&7)] (involution, both
// sides) — conflict-free ds_read_b128 (SQ_LDS_BANK_CONFLICT=0, R5-R11).
// Stage-halves == read-halves:
//   A-half h: rows {h*64..h*64+63} u {h*64+128..h*64+191}  (= LDA(h) rows)
//   B-half h: rows [h*32,(h+1)*32) mod 64 per wn-group     (= LDB2(2h) rows)
// ---------------------------------------------------------------------------

#define STG_A(buf, kt, h)                                                   \
  {                                                                         \
    const size_t ko = (size_t)(kt) * 64;                                    \
    gload_lds16(Ag + (size_t)((h) * 64) * HIDN + ko,                        \
                (void*)&As[buf][((h) * 64 + wave * 8) * 64]);               \
    gload_lds16(Ag + (size_t)((h) * 64 + 128) * HIDN + ko,                  \
                (void*)&As[buf][((h) * 64 + 128 + wave * 8) * 64]);         \
  }

#define STG_B(buf, kt, h)                                                   \
  {                                                                         \
    const int cb0 = (wave >> 2) * 64 + (h) * 32 + (wave & 3) * 8;           \
    const size_t ko = (size_t)(kt) * 64;                                    \
    gload_lds16(Bg + (size_t)cb0 * HIDN + ko,                               \
                (void*)&Bs[buf][cb0 * 64]);                                 \
    gload_lds16(Bg + (size_t)(cb0 + 128) * HIDN + ko,                       \
                (void*)&Bs[buf][(cb0 + 128) * 64]);                         \
  }

// load A-frags (4) for m-half mh from buffer rb into af[0..3][ks]
#define LDA(mh, rb)                                                         \
  {                                                                         \
    _Pragma("unroll") for (int f = 0; f < 4; f++) {                         \
      const int row = wm * 128 + (mh) * 64 + f * 16 + l16;                  \
      af[f][0] = *(const short8*)&As[rb][row * 64 + ((qd ^ ro) << 3)];      \
      af[f][1] =                                                            \
          *(const short8*)&As[rb][row * 64 + (((4 + qd) ^ ro) << 3)];       \
    }                                                                       \
  }

// load B-frags (2) j0..j0+1 from buffer rb into bfr[j0..j0+1][ks]
#define LDB2(j0, rb)                                                        \
  {                                                                         \
    _Pragma("unroll") for (int g = 0; g < 2; g++) {                         \
      const int col = wn * 64 + ((j0) + g) * 16 + l16;                      \
      bfr[(j0) + g][0] =                                                    \
          *(const short8*)&Bs[rb][col * 64 + ((qd ^ ro) << 3)];             \
      bfr[(j0) + g][1] =                                                    \
          *(const short8*)&Bs[rb][col * 64 + (((4 + qd) ^ ro) << 3)];       \
    }                                                                       \
  }

// MFMA one quadrant (mh, nh)
#define MQ(mh, nh)                                                          \
  {                                                                         \
    __builtin_amdgcn_s_setprio(1);                                          \
    _Pragma("unroll") for (int ks = 0; ks < 2; ks++)                        \
    _Pragma("unroll") for (int f = 0; f < 4; f++)                           \
    _Pragma("unroll") for (int g = 0; g < 2; g++)                           \
      acc[(mh) * 4 + f][(nh) * 2 + g] =                                     \
          __builtin_amdgcn_mfma_f32_16x16x32_bf16(                          \
              af[f][ks], bfr[(nh) * 2 + g][ks],                             \
              acc[(mh) * 4 + f][(nh) * 2 + g], 0, 0, 0);                    \
    __builtin_amdgcn_s_setprio(0);                                          \
  }

__device__ __forceinline__ void gemm256(const bf16_t* __restrict__ A,
                                        const bf16_t* __restrict__ Bw,
                                        const float*  __restrict__ bias,
                                        bf16_t* __restrict__ outb,
                                        float*  __restrict__ outf, int epi,
                                        int tm, int tn) {
  __shared__ short As[2][256 * 64];  // 64 KB
  __shared__ short Bs[2][256 * 64];  // 64 KB
  const int tid  = threadIdx.x;
  const int wave = tid >> 6;
  const int lane = tid & 63;
  const int wm   = wave >> 2;  // 0..1 -> 128 output rows each
  const int wn   = wave & 3;   // 0..3 -> 64 output cols each
  const int qd   = lane >> 4;
  const int l16  = lane & 15;
  const int ro   = l16 & 7;
  const int gc   = (lane & 7) ^ (lane >> 3);

  // A staging base includes wave*8 (STG_A row = h*64 [+128] + wave*8 + l>>3);
  // B staging base does NOT (cb0 encodes the wave offset).
  const short* Ag =
      (const short*)A + (size_t)(tm + wave * 8 + (lane >> 3)) * HIDN + gc * 8;
  const short* Bg =
      (const short*)Bw + (size_t)(tn + (lane >> 3)) * HIDN + gc * 8;

  f32x4 acc[8][4];
#pragma unroll
  for (int i = 0; i < 8; i++)
#pragma unroll
    for (int j = 0; j < 4; j++) acc[i][j] = (f32x4){0.f, 0.f, 0.f, 0.f};
  short8 af[4][2], bfr[4][2];

  // prologue: tile0's 4 halves in consumption order (Ah0,Bh0,Bh1,Ah1);
  // vmcnt(4) drains Ah0+Bh0, leaves Bh1+Ah1 in flight == steady p3-exit.
  STG_A(0, 0, 0); STG_B(0, 0, 0); STG_B(0, 0, 1); STG_A(0, 0, 1);
  VMW4;
  SBAR;

  // Steady ledger (outstanding loads after each phase's staging = 8):
  //  end-p0: VMW6 drains Bh1(t)   [staged p1(t-1), 4 phases prior]
  //  end-p1: VMW6 drains Ah1(t)   [staged p2(t-1), 4 phases prior]
  //  end-p3: VMW4 drains Ah0+Bh0(t+1) [staged p0(t), 4 phases prior]
  // Never below 4 outstanding until the t=31 tail (2 -> 0).
  for (int t = 0; t < 32; t++) {
    const int cur = t & 1, nx = cur ^ 1;
    // p0: reads Ah0 + B j01; stage Ah0(t+1) + Bh0(t+1)
    LDA(0, cur);
    LDB2(0, cur);
    if (t < 31) { STG_A(nx, t + 1, 0); STG_B(nx, t + 1, 0); }
    MQ(0, 0);
    if (t < 31) { VMW6; } else { VMW2; }
    SBAR;
    // p1: reads B j23; stage Bh1(t+1)
    LDB2(2, cur);
    if (t < 31) { STG_B(nx, t + 1, 1); }
    MQ(0, 1);
    if (t < 31) { VMW6; } else { VMW0; }
    SBAR;
    // p2: reads Ah1; stage Ah1(t+1)   (no barrier into p3)
    LDA(1, cur);
    if (t < 31) { STG_A(nx, t + 1, 1); }
    MQ(1, 1);
    // p3: no reads, no stagings
    MQ(1, 0);
    if (t < 31) { VMW4; SBAR; }
  }

  // epilogue: row = tm + wm*128 + (i>>2)*64 + (i&3)*16 + qd*4 + r
  //           col = tn + wn*64 + j*16 + l16
#pragma unroll
  for (int i = 0; i < 8; i++)
#pragma unroll
    for (int j = 0; j < 4; j++)
#pragma unroll
      for (int r = 0; r < 4; r++) {
        const int row =
            tm + wm * 128 + (i >> 2) * 64 + (i & 3) * 16 + qd * 4 + r;
        const int col = tn + wn * 64 + j * 16 + l16;
        float v = acc[i][j][r];
        if (epi == 1) {
          v += bias[col];
          const float ls = fminf(v, 0.f) - log1pf(__expf(-fabsf(v)));
          v = fmaxf(ls * 0.0625f, -50.f);
        }
        if (epi == 2) outf[(size_t)row * HIDN + col] = v;
        else          outb[(size_t)row * HIDN + col] = (bf16_t)v;
      }
}

// XCD-aware block swizzle: dispatch index lid round-robins XCDs (lid%8,
// z-independent since 128 blocks/z). Give XCD k a 4x4 spatial cluster so
// co-L2 blocks share 4 A-panels + 4 B-panels. Bijective on [0,128).
__device__ __forceinline__ void xcd_swz(int lid, int& bx, int& by) {
  const int k = lid & 7, u = lid >> 3;
  bx = (k & 3) * 4 + (u & 3);   // 0..15
  by = (k >> 2) * 4 + (u >> 2); // 0..7
}

__global__ __launch_bounds__(512, 2) void k_gemm_proj(
    const bf16_t* __restrict__ Xb,
    const bf16_t* __restrict__ W0, const bf16_t* __restrict__ W1,
    const bf16_t* __restrict__ W2, const bf16_t* __restrict__ W3,
    const bf16_t* __restrict__ W4,
    const float* __restrict__ bg1, const float* __restrict__ bg2,
    bf16_t* __restrict__ Qb, bf16_t* __restrict__ Kb, bf16_t* __restrict__ Vb,
    bf16_t* __restrict__ G1b, bf16_t* __restrict__ G2b) {
  const int z = blockIdx.z;
  const bf16_t* Ws[5] = {W0, W1, W2, W3, W4};
  bf16_t* Os[5] = {Qb, Kb, Vb, G1b, G2b};
  const float* bias = (z == 3) ? bg1 : ((z == 4) ? bg2 : nullptr);
  int bx, by;
  xcd_swz(blockIdx.y * 16 + blockIdx.x, bx, by);
  gemm256(Xb, Ws[z], bias, Os[z], nullptr, (z >= 3) ? 1 : 0, bx * 256,
          by * 256);
}

__global__ __launch_bounds__(512, 2) void k_gemm_out(
    const bf16_t* __restrict__ attnB, const bf16_t* __restrict__ Wob,
    float* __restrict__ out) {
  int bx, by;
  xcd_swz(blockIdx.y * 16 + blockIdx.x, bx, by);
  gemm256(attnB, Wob, nullptr, nullptr, out, 2, bx * 256, by * 256);
}

// ---------------------------------------------------------------------------
__global__ __launch_bounds__(256) void k_cvt_all(
    const float* __restrict__ hid, const float* __restrict__ wq,
    const float* __restrict__ wk, const float* __restrict__ wv,
    const float* __restrict__ wg1, const float* __restrict__ wg2,
    const float* __restrict__ wo, bf16_t* __restrict__ Xb,
    bf16_t* __restrict__ Wd, bf16_t* __restrict__ Wcur,
    bf16_t* __restrict__ WoB) {
  const int y = blockIdx.y;
  const float* srcs[7] = {hid, wq, wk, wv, wg1, wg2, wo};
  bf16_t* dsts[7] = {Xb, Wd, Wd + WELC, Wd + 2 * WELC, Wd + 3 * WELC, Wcur,
                     WoB};
  const int n = (y == 0) ? NELC : WELC;
  const float* src = srcs[y];
  bf16_t* dst = dsts[y];
  const int idx = (blockIdx.x * 256 + threadIdx.x) * 4;
  if (idx < n) {
    const float4 f = *(const float4*)(src + idx);
    dst[idx + 0] = (bf16_t)f.x; dst[idx + 1] = (bf16_t)f.y;
    dst[idx + 2] = (bf16_t)f.z; dst[idx + 3] = (bf16_t)f.w;
  }
}

__global__ __launch_bounds__(256) void k_zero(float* __restrict__ out) {
  out[(size_t)blockIdx.x * 256 + threadIdx.x] = 0.f;
}

// ---------------------------------------------------------------------------
// k_gc: per-chunk inclusive cumsum of gate values along t (fp32 accum),
// stored fp16 IN PLACE over G; chunk totals to Btot (fp32).
// grid (NCHUNK, BB*4, 2), 64 threads. Fully coalesced b128.
// ---------------------------------------------------------------------------
__global__ __launch_bounds__(64) void k_gc(bf16_t* __restrict__ G1b,
                                           bf16_t* __restrict__ G2b,
                                           float* __restrict__ Btot) {
  const int n = blockIdx.x, b = blockIdx.y >> 2, slab = blockIdx.y & 3;
  const int e = blockIdx.z;
  short* P = (short*)(e ? G2b : G1b);
  const int d0 = slab * 512 + threadIdx.x * 8;
  const size_t base = ((size_t)(b * SEQ + n * CHUNK)) * HIDN + d0;
  float c[8] = {0.f, 0.f, 0.f, 0.f, 0.f, 0.f, 0.f, 0.f};
  for (int t = 0; t < CHUNK; t++) {
    short* p = P + base + (size_t)t * HIDN;
    const short8 g = *(const short8*)p;
    short8 o;
#pragma unroll
    for (int j = 0; j < 8; j++) { c[j] += bf2f(g[j]); o[j] = f2hf(c[j]); }
    *(short8*)p = o;
  }
  const int bh = b * 16 + (d0 >> 7);
  float* bp = Btot + ((size_t)(e * NBH + bh) * NCHUNK + n) * DD + (d0 & 127);
#pragma unroll
  for (int j = 0; j < 8; j++) bp[j] = c[j];
}

// ---------------------------------------------------------------------------
// k_sA (per e): fused U-build + intra-chunk output.
//   vT[dv][s](pad66), khatT[dk][s](pad66), k2[s][d](swz), qh[t][d](swz),
//   Ps[t][s](pad72).  U = vT x khatT -> UT global (chunk-swizzled rows).
//   P = qh x k2 (causal), o_intra = Ps x vT -> attn (w_e folded).
// ---------------------------------------------------------------------------
template <int ACC>
__global__ __launch_bounds__(256) void k_sA(
    const bf16_t* __restrict__ Qb, const bf16_t* __restrict__ Kb,
    const bf16_t* __restrict__ Vb, const bf16_t* __restrict__ Gc,
    bf16_t* __restrict__ UT, const float* __restrict__ alpha,
    bf16_t* __restrict__ attn) {
  const int n = blockIdx.x, bh = blockIdx.y;
  const int b = bh >> 4, h = bh & 15;
  const size_t rbase = ((size_t)(b * SEQ + n * CHUNK)) * HIDN + h * DD;
  const int tid = threadIdx.x;
  const int wave = tid >> 6, lane = tid & 63, qd = lane >> 4, l16 = lane & 15;
  __shared__ short vT[128 * 66];
  __shared__ short k2s[64 * 128];
  __shared__ short r3[128 * 66];  // khatT, then reused as qh (64*128 prefix)
  __shared__ short Ps[64 * 72];
  const float mx = fmaxf(alpha[0], alpha[1]);
  const float x0 = __expf(alpha[0] - mx), x1 = __expf(alpha[1] - mx);
  const float wsc = ((ACC ? x1 : x0) / (x0 + x1)) * QSCALE;

  const short* Kp = (const short*)Kb;
  const short* Vp = (const short*)Vb;
  const short* Gp = (const short*)Gc;
  const short* Qp = (const short*)Qb;

  // builds: vT (col-writes, bank d mod 32), k2 (swz b128), khatT (col-writes)
#pragma unroll
  for (int rep = 0; rep < 4; rep++) {
    const int slot = rep * 256 + tid;
    const int t = slot >> 4, ch = slot & 15;
    const size_t ga = rbase + (size_t)t * HIDN + ch * 8;
    const short8 vv = *(const short8*)(Vp + ga);
    const short8 kk = *(const short8*)(Kp + ga);
    const short8 cc = *(const short8*)(Gp + ga);
    const short8 c6 = *(const short8*)(Gp + rbase + (size_t)63 * HIDN + ch * 8);
    short8 k2v;
#pragma unroll
    for (int j = 0; j < 8; j++) {
      const int d = ch * 8 + j;
      vT[d * 66 + t] = vv[j];
      const float c = hf2f(cc[j]);
      const float kf = bf2f(kk[j]);
      k2v[j] = f2bf(kf * __expf(-c));
      r3[d * 66 + t] = f2bf(kf * __expf(hf2f(c6[j]) - c));
    }
    *(short8*)&k2s[t * 128 + ((ch ^ (t & 7)) << 3)] = k2v;
  }
  __syncthreads();

  {  // U-MFMA: C[dv][dk] = sum_s vT[dv][s] * khatT[dk][s]
    const int m0 = (wave >> 1) * 64, n0 = (wave & 1) * 64;
    const int* vTi = (const int*)vT;
    const int* r3i = (const int*)r3;
    f32x4 uacc[4][4];
#pragma unroll
    for (int i = 0; i < 4; i++)
#pragma unroll
      for (int j = 0; j < 4; j++) uacc[i][j] = (f32x4){0.f, 0.f, 0.f, 0.f};
#pragma unroll
    for (int ks = 0; ks < 2; ks++) {
      const int ch = ks * 4 + qd;
      short8 af[4], bfv[4];
#pragma unroll
      for (int i = 0; i < 4; i++) {
        const int dv = m0 + i * 16 + l16;
        const int ba = dv * 33 + ch * 4;
#pragma unroll
        for (int w2 = 0; w2 < 4; w2++) {
          const int v = vTi[ba + w2];
          af[i][2 * w2] = (short)(v & 0xffff);
          af[i][2 * w2 + 1] = (short)((unsigned)v >> 16);
        }
      }
#pragma unroll
      for (int j = 0; j < 4; j++) {
        const int dk = n0 + j * 16 + l16;
        const int ba = dk * 33 + ch * 4;
#pragma unroll
        for (int w2 = 0; w2 < 4; w2++) {
          const int v = r3i[ba + w2];
          bfv[j][2 * w2] = (short)(v & 0xffff);
          bfv[j][2 * w2 + 1] = (short)((unsigned)v >> 16);
        }
      }
#pragma unroll
      for (int i = 0; i < 4; i++)
#pragma unroll
        for (int j = 0; j < 4; j++)
          uacc[i][j] = __builtin_amdgcn_mfma_f32_16x16x32_bf16(
              af[i], bfv[j], uacc[i][j], 0, 0, 0);
    }
    short* Uo = (short*)UT + (size_t)(bh * NCHUNK + n) * (DD * DD);
#pragma unroll
    for (int i = 0; i < 4; i++)
#pragma unroll
      for (int j = 0; j < 4; j++)
#pragma unroll
        for (int r = 0; r < 4; r++) {
          const int dv = m0 + i * 16 + qd * 4 + r;
          const int dk = n0 + j * 16 + l16;
          Uo[dv * 128 + (((dk >> 3) ^ (dv & 7)) << 3) + (dk & 7)] =
              f2bf(uacc[i][j][r]);
        }
  }
  __syncthreads();

  // qh build (overwrites khatT region)
#pragma unroll
  for (int rep = 0; rep < 4; rep++) {
    const int slot = rep * 256 + tid;
    const int t = slot >> 4, ch = slot & 15;
    const size_t ga = rbase + (size_t)t * HIDN + ch * 8;
    const short8 qq = *(const short8*)(Qp + ga);
    const short8 cc = *(const short8*)(Gp + ga);
    short8 o;
#pragma unroll
    for (int j = 0; j < 8; j++)
      o[j] = f2bf(bf2f(qq[j]) * wsc * __expf(hf2f(cc[j])));
    *(short8*)&r3[t * 128 + ((ch ^ (t & 7)) << 3)] = o;
  }
  __syncthreads();

  {  // P = qh x k2 (causal): wave owns t-rows [wave*16, +16)
    f32x4 pacc[4];
#pragma unroll
    for (int j = 0; j < 4; j++) pacc[j] = (f32x4){0.f, 0.f, 0.f, 0.f};
    const int tq = wave * 16 + l16;
#pragma unroll
    for (int ks = 0; ks < 4; ks++) {
      const int ch = ks * 4 + qd;
      const short8 a = *(const short8*)&r3[tq * 128 + ((ch ^ (tq & 7)) << 3)];
#pragma unroll
      for (int j = 0; j < 4; j++) {
        const int s = j * 16 + l16;
        const short8 bq =
            *(const short8*)&k2s[s * 128 + ((ch ^ (s & 7)) << 3)];
        pacc[j] =
            __builtin_amdgcn_mfma_f32_16x16x32_bf16(a, bq, pacc[j], 0, 0, 0);
      }
    }
#pragma unroll
    for (int j = 0; j < 4; j++)
#pragma unroll
      for (int r = 0; r < 4; r++) {
        const int t = wave * 16 + qd * 4 + r, s = j * 16 + l16;
        Ps[t * 72 + s] = (t >= s) ? f2bf(pacc[j][r]) : (short)0;
      }
  }
  __syncthreads();

  // o_intra = Ps x vT
  f32x4 oacc[8];
#pragma unroll
  for (int j = 0; j < 8; j++) oacc[j] = (f32x4){0.f, 0.f, 0.f, 0.f};
  {
    const int* vTi = (const int*)vT;
    const int tq = wave * 16 + l16;
#pragma unroll
    for (int ks = 0; ks < 2; ks++) {
      const int ch = ks * 4 + qd;
      const short8 a = *(const short8*)&Ps[tq * 72 + ch * 8];
#pragma unroll
      for (int j = 0; j < 8; j++) {
        const int dv = j * 16 + l16;
        const int ba = dv * 33 + ch * 4;
        short8 bq;
#pragma unroll
        for (int w2 = 0; w2 < 4; w2++) {
          const int v = vTi[ba + w2];
          bq[2 * w2] = (short)(v & 0xffff);
          bq[2 * w2 + 1] = (short)((unsigned)v >> 16);
        }
        oacc[j] =
            __builtin_amdgcn_mfma_f32_16x16x32_bf16(a, bq, oacc[j], 0, 0, 0);
      }
    }
  }
#pragma unroll
  for (int j = 0; j < 8; j++)
#pragma unroll
    for (int r = 0; r < 4; r++) {
      const int t = wave * 16 + qd * 4 + r;
      const int dv = j * 16 + l16;
      bf16_t* p = &attn[rbase + (size_t)t * HIDN + dv];
      if (ACC) *p = (bf16_t)((float)*p + oacc[j][r]);
      else     *p = (bf16_t)oacc[j][r];
    }
}

// ---------------------------------------------------------------------------
// k_s2: sequential chunk combine (swizzled UT rows); S^T in place.
// ---------------------------------------------------------------------------
__global__ __launch_bounds__(256) void k_s2(bf16_t* __restrict__ UT,
                                            const float* __restrict__ Btot) {
  const int dg = blockIdx.x, bh = blockIdx.y;
  const int dv = dg * 8 + (threadIdx.x >> 5);
  const int dk0 = (threadIdx.x & 31) * 4;
  const int pos = dv * 128 + (((dk0 >> 3) ^ (dv & 7)) << 3) + (dk0 & 7);
  float st[4] = {0.f, 0.f, 0.f, 0.f};
  for (int nn = 0; nn < NCHUNK; nn++) {
    short* p = (short*)UT + (size_t)(bh * NCHUNK + nn) * (DD * DD) + pos;
    const float4 bp =
        *(const float4*)(Btot + (size_t)(bh * NCHUNK + nn) * DD + dk0);
    short u0 = p[0], u1 = p[1], u2 = p[2], u3 = p[3];
    p[0] = f2bf(st[0]); p[1] = f2bf(st[1]);
    p[2] = f2bf(st[2]); p[3] = f2bf(st[3]);
    st[0] = st[0] * __expf(bp.x) + bf2f(u0);
    st[1] = st[1] * __expf(bp.y) + bf2f(u1);
    st[2] = st[2] * __expf(bp.z) + bf2f(u2);
    st[3] = st[3] * __expf(bp.w) + bf2f(u3);
  }
}

// ---------------------------------------------------------------------------
// k_s3b: inter-chunk  attn += qh @ S.  S staged via gload16 (async, overlaps
// qh rebuild); both read as swizzled b128 frags.
// ---------------------------------------------------------------------------
__global__ __launch_bounds__(256) void k_s3b(
    const bf16_t* __restrict__ Qb, const bf16_t* __restrict__ Gc,
    const bf16_t* __restrict__ UT, const float* __restrict__ alpha,
    const int e, bf16_t* __restrict__ attn) {
  const int n = blockIdx.x, bh = blockIdx.y;
  const int b = bh >> 4, h = bh & 15;
  const size_t rbase = ((size_t)(b * SEQ + n * CHUNK)) * HIDN + h * DD;
  const int tid = threadIdx.x;
  const int wave = tid >> 6, lane = tid & 63, qd = lane >> 4, l16 = lane & 15;
  __shared__ short qh[64 * 128];
  __shared__ short Ss[128 * 128];
  const float mx = fmaxf(alpha[0], alpha[1]);
  const float x0 = __expf(alpha[0] - mx), x1 = __expf(alpha[1] - mx);
  const float wsc = ((e ? x1 : x0) / (x0 + x1)) * QSCALE;

  // async-stage S tile (2048 x 16B chunks, lane-linear, layout preserved)
  const short* Sp = (const short*)UT + (size_t)(bh * NCHUNK + n) * (DD * DD);
#pragma unroll
  for (int rep = 0; rep < 8; rep++) {
    const int c = rep * 256 + tid;
    gload_lds16(Sp + c * 8, &Ss[c * 8]);
  }
  // qh rebuild (overlaps the async loads)
  const short* Qp = (const short*)Qb;
  const short* Gp = (const short*)Gc;
#pragma unroll
  for (int rep = 0; rep < 4; rep++) {
    const int slot = rep * 256 + tid;
    const int t = slot >> 4, ch = slot & 15;
    const size_t ga = rbase + (size_t)t * HIDN + ch * 8;
    const short8 qq = *(const short8*)(Qp + ga);
    const short8 cc = *(const short8*)(Gp + ga);
    short8 o;
#pragma unroll
    for (int j = 0; j < 8; j++)
      o[j] = f2bf(bf2f(qq[j]) * wsc * __expf(hf2f(cc[j])));
    *(short8*)&qh[t * 128 + ((ch ^ (t & 7)) << 3)] = o;
  }
  __syncthreads();

  f32x4 oacc[8];
#pragma unroll
  for (int j = 0; j < 8; j++) oacc[j] = (f32x4){0.f, 0.f, 0.f, 0.f};
  const int tq = wave * 16 + l16;
#pragma unroll
  for (int ks = 0; ks < 4; ks++) {
    const int ch = ks * 4 + qd;
    const short8 a = *(const short8*)&qh[tq * 128 + ((ch ^ (tq & 7)) << 3)];
#pragma unroll
    for (int j = 0; j < 8; j++) {
      const int dv = j * 16 + l16;
      const short8 bq = *(const short8*)&Ss[dv * 128 + ((ch ^ (dv & 7)) << 3)];
      oacc[j] =
          __builtin_amdgcn_mfma_f32_16x16x32_bf16(a, bq, oacc[j], 0, 0, 0);
    }
  }
#pragma unroll
  for (int j = 0; j < 8; j++)
#pragma unroll
    for (int r = 0; r < 4; r++) {
      const int t = wave * 16 + qd * 4 + r;
      const int dv = j * 16 + l16;
      bf16_t* p = &attn[rbase + (size_t)t * HIDN + dv];
      *p = (bf16_t)((float)*p + oacc[j][r]);
    }
}

// ---------------------------------------------------------------------------
extern "C" void kernel_launch(void* const* d_in, const int* in_sizes, int n_in,
                              void* d_out, int out_size, void* d_ws,
                              size_t ws_size, hipStream_t stream) {
  const float* hid  = (const float*)d_in[0];
  const float* wq   = (const float*)d_in[1];
  const float* wk   = (const float*)d_in[2];
  const float* wv   = (const float*)d_in[3];
  const float* wo   = (const float*)d_in[4];
  const float* wg1  = (const float*)d_in[5];
  const float* bg1  = (const float*)d_in[6];
  const float* wg2  = (const float*)d_in[7];
  const float* bg2  = (const float*)d_in[8];
  const float* alph = (const float*)d_in[9];
  float* out = (float*)d_out;
  (void)in_sizes; (void)n_in; (void)out_size;

  char* ws = (char*)d_ws;
  size_t off = 0;
  auto alloc = [&](size_t bytes) -> void* {
    void* p = ws + off;
    off += (bytes + 255) & ~(size_t)255;
    return p;
  };
  const size_t NEL = NELC, WEL = WELC;
  bf16_t* Xb   = (bf16_t*)alloc(NEL * 2);  // X; reused as attn
  bf16_t* Wcur = (bf16_t*)alloc(WEL * 2);  // Wg2
  bf16_t* WoB  = (bf16_t*)alloc(WEL * 2);  // Wo
  bf16_t* Qb   = (bf16_t*)alloc(NEL * 2);
  bf16_t* Kb   = (bf16_t*)alloc(NEL * 2);
  bf16_t* Vb   = (bf16_t*)alloc(NEL * 2);
  bf16_t* G1b  = (bf16_t*)alloc(NEL * 2);
  bf16_t* G2b  = (bf16_t*)alloc(NEL * 2);
  float*  Btot = (float*) alloc((size_t)2 * NBH * NCHUNK * DD * 4);
  bf16_t* Wd = (bf16_t*)d_out;  // weights, then U/S states, then final out
  bf16_t* UT = (bf16_t*)d_out;

  if (off > ws_size) {  // diagnostic fallback
    k_zero<<<dim3((unsigned)(NEL / 256)), 256, 0, stream>>>(out);
    return;
  }

  k_cvt_all<<<dim3(8192, 7), 256, 0, stream>>>(hid, wq, wk, wv, wg1, wg2, wo,
                                               Xb, Wd, Wcur, WoB);
  k_gemm_proj<<<dim3(16, 8, 5), 512, 0, stream>>>(
      Xb, Wd, Wd + WEL, Wd + 2 * WEL, Wd + 3 * WEL, Wcur, bg1, bg2, Qb, Kb, Vb,
      G1b, G2b);
  k_gc<<<dim3(NCHUNK, BB * 4, 2), 64, 0, stream>>>(G1b, G2b, Btot);

  const dim3 gs(NCHUNK, NBH), g2(16, NBH);
  const size_t BSTRIDE = (size_t)NBH * NCHUNK * DD;
  // e = 0
  k_sA<0><<<gs, 256, 0, stream>>>(Qb, Kb, Vb, G1b, UT, alph, Xb);
  k_s2<<<g2, 256, 0, stream>>>(UT, Btot);
  k_s3b<<<gs, 256, 0, stream>>>(Qb, G1b, UT, alph, 0, Xb);
  // e = 1
  k_sA<1><<<gs, 256, 0, stream>>>(Qb, Kb, Vb, G2b, UT, alph, Xb);
  k_s2<<<g2, 256, 0, stream>>>(UT, Btot + BSTRIDE);
  k_s3b<<<gs, 256, 0, stream>>>(Qb, G2b, UT, alph, 1, Xb);

  k_gemm_out<<<dim3(16, 8), 512, 0, stream>>>(Xb, WoB, out);
}